// Round 5
// baseline (228.677 us; speedup 1.0000x reference)
//
#include <hip/hip_runtime.h>
#include <hip/hip_bf16.h>
#include <stdint.h>

#define HID 2048
#define NH  32
#define HD  64
#define NB  8
#define NS  16
#define PAST 4096

// log2(e) / sqrt(D) = 1.4426950408889634 / 8
#define QSCALE 0.18033688011112042591f

typedef __attribute__((ext_vector_type(8))) short short8;
typedef __attribute__((ext_vector_type(4))) short short4v;
typedef __attribute__((ext_vector_type(4))) float f32x4;

#define MFMA(a, b, c) __builtin_amdgcn_mfma_f32_16x16x32_bf16((a), (b), (c), 0, 0, 0)

#define PART_STRIDE 1088  // 16 m + 16 l + 16*64 O + pad, floats
#define NSPLIT 8          // attn splits per (b,h); 512 pos per split

static __device__ __forceinline__ short f2bf(float f) {
    __hip_bfloat16 h = __float2bfloat16(f);
    return *reinterpret_cast<short*>(&h);
}

static __device__ __forceinline__ short8 pack8(float4 a, float4 b) {
    short8 r;
    r[0] = f2bf(a.x); r[1] = f2bf(a.y); r[2] = f2bf(a.z); r[3] = f2bf(a.w);
    r[4] = f2bf(b.x); r[5] = f2bf(b.y); r[6] = f2bf(b.z); r[7] = f2bf(b.w);
    return r;
}

static __device__ __forceinline__ short8 pack8s(float4 a, float4 b, float s) {
    short8 r;
    r[0] = f2bf(a.x * s); r[1] = f2bf(a.y * s); r[2] = f2bf(a.z * s); r[3] = f2bf(a.w * s);
    r[4] = f2bf(b.x * s); r[5] = f2bf(b.y * s); r[6] = f2bf(b.z * s); r[7] = f2bf(b.w * s);
    return r;
}

// ---------------- hidden fp32 -> bf16 ----------------
__global__ __launch_bounds__(256) void cvt_kernel(const float* __restrict__ in,
                                                  short* __restrict__ out) {
    int i = (blockIdx.x * 256 + threadIdx.x) * 4;
    float4 v = *reinterpret_cast<const float4*>(in + i);
    short4v o;
    o[0] = f2bf(v.x); o[1] = f2bf(v.y); o[2] = f2bf(v.z); o[3] = f2bf(v.w);
    *reinterpret_cast<short4v*>(out + i) = o;
}

// ------- Y += Xbf16 @ W^T  (M=128, K-split x4, N=16 per block), atomic -----
// blockIdx.x = mat*512 + strip*4 + ks.  128 threads (2 waves, M=64 each).
__global__ __launch_bounds__(128) void proj_kernel(
        const short* __restrict__ X,
        const float* __restrict__ W0, const float* __restrict__ W1,
        const float* __restrict__ W2,
        float* __restrict__ Y0, float* __restrict__ Y1, float* __restrict__ Y2) {
    int mat   = blockIdx.x >> 9;
    int rest  = blockIdx.x & 511;
    int strip = rest >> 2, ks = rest & 3;
    int nbase = strip * 16;
    int k0    = ks * 512;
    const float* W = (mat == 0) ? W0 : (mat == 1) ? W1 : W2;
    float*       Y = (mat == 0) ? Y0 : (mat == 1) ? Y1 : Y2;

    int lane = threadIdx.x & 63;
    int wave = threadIdx.x >> 6;
    int lr = lane & 15, g = lane >> 4;

    f32x4 acc0 = {0.f, 0.f, 0.f, 0.f};
    f32x4 acc1 = {0.f, 0.f, 0.f, 0.f};
    f32x4 acc2 = {0.f, 0.f, 0.f, 0.f};
    f32x4 acc3 = {0.f, 0.f, 0.f, 0.f};

    const short* xr = X + (size_t)(wave * 64 + lr) * HID + g * 8 + k0;
    const float* wr = W + (size_t)(nbase + lr) * HID + g * 8 + k0;

    #pragma unroll 4
    for (int kc = 0; kc < 512; kc += 32) {
        float4 w0 = *reinterpret_cast<const float4*>(wr + kc);
        float4 w1 = *reinterpret_cast<const float4*>(wr + kc + 4);
        short8 bb = pack8(w0, w1);
        short8 a0 = *reinterpret_cast<const short8*>(xr + kc);
        short8 a1 = *reinterpret_cast<const short8*>(xr + (size_t)16 * HID + kc);
        short8 a2 = *reinterpret_cast<const short8*>(xr + (size_t)32 * HID + kc);
        short8 a3 = *reinterpret_cast<const short8*>(xr + (size_t)48 * HID + kc);
        acc0 = MFMA(a0, bb, acc0);
        acc1 = MFMA(a1, bb, acc1);
        acc2 = MFMA(a2, bb, acc2);
        acc3 = MFMA(a3, bb, acc3);
    }
    #define STACC(accv, f) do { \
        atomicAdd(&Y[(size_t)(wave * 64 + (f) * 16 + (g << 2) + 0) * HID + nbase + lr], accv[0]); \
        atomicAdd(&Y[(size_t)(wave * 64 + (f) * 16 + (g << 2) + 1) * HID + nbase + lr], accv[1]); \
        atomicAdd(&Y[(size_t)(wave * 64 + (f) * 16 + (g << 2) + 2) * HID + nbase + lr], accv[2]); \
        atomicAdd(&Y[(size_t)(wave * 64 + (f) * 16 + (g << 2) + 3) * HID + nbase + lr], accv[3]); \
    } while (0)
    STACC(acc0, 0); STACC(acc1, 1); STACC(acc2, 2); STACC(acc3, 3);
    #undef STACC
}

// ---------------- fused attention, 8 blocks per (b,h) -------------------
// blockIdx.x = bh*8 + split. 256 threads = 4 waves; wave w owns pos
// [split*512 + w*128, +128) = 2 tiles of 64.
__global__ __launch_bounds__(256, 8) void attn_kernel(
        const float* __restrict__ q,
        const float* __restrict__ knew, const float* __restrict__ vnew,
        const float* __restrict__ pastK, const float* __restrict__ pastV,
        float* __restrict__ parts) {
    int bid = blockIdx.x;
    int bh = bid >> 3, split = bid & 7;
    int b = bh >> 5, h = bh & 31;
    int wave = threadIdx.x >> 6, lane = threadIdx.x & 63;
    int lq = lane & 15, g = lane >> 4;

    // Q fragments (B operand of swapped QK^T), pre-scaled by log2(e)/8
    const float* qp = q + (size_t)(b * NS + lq) * HID + h * HD + g * 8;
    short8 qf0, qf1;
    {
        float4 a0 = *reinterpret_cast<const float4*>(qp);
        float4 a1 = *reinterpret_cast<const float4*>(qp + 4);
        float4 a2 = *reinterpret_cast<const float4*>(qp + 32);
        float4 a3 = *reinterpret_cast<const float4*>(qp + 36);
        qf0 = pack8s(a0, a1, QSCALE);
        qf1 = pack8s(a2, a3, QSCALE);
    }

    f32x4 o0 = {0.f, 0.f, 0.f, 0.f};
    f32x4 o1 = {0.f, 0.f, 0.f, 0.f};
    f32x4 o2 = {0.f, 0.f, 0.f, 0.f};
    f32x4 o3 = {0.f, 0.f, 0.f, 0.f};
    float m = -__builtin_inff(), lsum = 0.0f;

    const float* kbase = pastK + (size_t)bh * PAST * HD + (size_t)(split * 512 + wave * 128) * HD;
    const float* vbase = pastV + (size_t)bh * PAST * HD + (size_t)(split * 512 + wave * 128) * HD;

    // V gather: dst[j] = V[kfo + (j>=4?16:0) + g*4 + (j&3)][dcol], bf16
    #define LOADV8(dst, vtp, kfo, dcol) do { \
        dst[0] = f2bf((vtp)[(size_t)((kfo) + (g << 2) + 0) * HD + (dcol)]); \
        dst[1] = f2bf((vtp)[(size_t)((kfo) + (g << 2) + 1) * HD + (dcol)]); \
        dst[2] = f2bf((vtp)[(size_t)((kfo) + (g << 2) + 2) * HD + (dcol)]); \
        dst[3] = f2bf((vtp)[(size_t)((kfo) + (g << 2) + 3) * HD + (dcol)]); \
        dst[4] = f2bf((vtp)[(size_t)((kfo) + 16 + (g << 2) + 0) * HD + (dcol)]); \
        dst[5] = f2bf((vtp)[(size_t)((kfo) + 16 + (g << 2) + 1) * HD + (dcol)]); \
        dst[6] = f2bf((vtp)[(size_t)((kfo) + 16 + (g << 2) + 2) * HD + (dcol)]); \
        dst[7] = f2bf((vtp)[(size_t)((kfo) + 16 + (g << 2) + 3) * HD + (dcol)]); \
    } while (0)

    #define QKSUB(scv, s2i) do { \
        const float* kr = kbase + (size_t)(pb + (s2i) * 16 + lq) * HD + (g << 3); \
        float4 ka = *reinterpret_cast<const float4*>(kr); \
        float4 kb2 = *reinterpret_cast<const float4*>(kr + 4); \
        float4 kc2 = *reinterpret_cast<const float4*>(kr + 32); \
        float4 kd2 = *reinterpret_cast<const float4*>(kr + 36); \
        short8 af0 = pack8(ka, kb2); \
        short8 af1 = pack8(kc2, kd2); \
        f32x4 sv = {0.f, 0.f, 0.f, 0.f}; \
        sv = MFMA(af0, qf0, sv); \
        sv = MFMA(af1, qf1, sv); \
        scv = sv; \
    } while (0)

    #define PEXP(dst, idx, sv, r) do { \
        float e = exp2f(sv[r] - mn); rsum += e; dst[idx] = f2bf(e); \
    } while (0)

    #pragma unroll 1
    for (int t = 0; t < 2; ++t) {
        int pb = t * 64;

        // ---- V fragments first (independent; loads overlap QK compute) ----
        const float* vt = vbase + (size_t)pb * HD;
        short8 vf0, vf1, vf2, vf3, vf4, vf5, vf6, vf7;
        LOADV8(vf0, vt, 0,  lq);       LOADV8(vf1, vt, 32, lq);
        LOADV8(vf2, vt, 0,  16 + lq);  LOADV8(vf3, vt, 32, 16 + lq);
        LOADV8(vf4, vt, 0,  32 + lq);  LOADV8(vf5, vt, 32, 32 + lq);
        LOADV8(vf6, vt, 0,  48 + lq);  LOADV8(vf7, vt, 32, 48 + lq);

        // ---- scores: S^T[pos][q] via mfma(K_tile, Q) ----
        f32x4 sc0, sc1, sc2, sc3;
        QKSUB(sc0, 0); QKSUB(sc1, 1); QKSUB(sc2, 2); QKSUB(sc3, 3);

        // ---- online softmax (per query = lane&15, partners l^16, l^32) ----
        float tmax = fmaxf(
            fmaxf(fmaxf(fmaxf(sc0[0], sc0[1]), fmaxf(sc0[2], sc0[3])),
                  fmaxf(fmaxf(sc1[0], sc1[1]), fmaxf(sc1[2], sc1[3]))),
            fmaxf(fmaxf(fmaxf(sc2[0], sc2[1]), fmaxf(sc2[2], sc2[3])),
                  fmaxf(fmaxf(sc3[0], sc3[1]), fmaxf(sc3[2], sc3[3]))));
        tmax = fmaxf(tmax, __shfl_xor(tmax, 16));
        tmax = fmaxf(tmax, __shfl_xor(tmax, 32));
        float mn = fmaxf(m, tmax);
        float alpha = exp2f(m - mn);
        float rsum = 0.f;
        short8 pf0, pf1;
        PEXP(pf0, 0, sc0, 0); PEXP(pf0, 1, sc0, 1); PEXP(pf0, 2, sc0, 2); PEXP(pf0, 3, sc0, 3);
        PEXP(pf0, 4, sc1, 0); PEXP(pf0, 5, sc1, 1); PEXP(pf0, 6, sc1, 2); PEXP(pf0, 7, sc1, 3);
        PEXP(pf1, 0, sc2, 0); PEXP(pf1, 1, sc2, 1); PEXP(pf1, 2, sc2, 2); PEXP(pf1, 3, sc2, 3);
        PEXP(pf1, 4, sc3, 0); PEXP(pf1, 5, sc3, 1); PEXP(pf1, 6, sc3, 2); PEXP(pf1, 7, sc3, 3);
        rsum += __shfl_xor(rsum, 16);
        rsum += __shfl_xor(rsum, 32);
        lsum = lsum * alpha + rsum;
        m = mn;
        o0 *= alpha; o1 *= alpha; o2 *= alpha; o3 *= alpha;

        // ---- PV: O^T[d][q] += V^T frags x P^T ----
        o0 = MFMA(vf0, pf0, o0); o0 = MFMA(vf1, pf1, o0);
        o1 = MFMA(vf2, pf0, o1); o1 = MFMA(vf3, pf1, o1);
        o2 = MFMA(vf4, pf0, o2); o2 = MFMA(vf5, pf1, o2);
        o3 = MFMA(vf6, pf0, o3); o3 = MFMA(vf7, pf1, o3);
    }

    // ---- the 16 new tokens (wave 0 of split-0 block) ----
    if (split == 0 && wave == 0) {
        const float* kr = knew + (size_t)(b * NS + lq) * HID + h * HD + g * 8;
        float4 ka = *reinterpret_cast<const float4*>(kr);
        float4 kb2 = *reinterpret_cast<const float4*>(kr + 4);
        float4 kc2 = *reinterpret_cast<const float4*>(kr + 32);
        float4 kd2 = *reinterpret_cast<const float4*>(kr + 36);
        short8 af0 = pack8(ka, kb2);
        short8 af1 = pack8(kc2, kd2);
        f32x4 sv = {0.f, 0.f, 0.f, 0.f};
        sv = MFMA(af0, qf0, sv);
        sv = MFMA(af1, qf1, sv);

        float tmax = fmaxf(fmaxf(sv[0], sv[1]), fmaxf(sv[2], sv[3]));
        tmax = fmaxf(tmax, __shfl_xor(tmax, 16));
        tmax = fmaxf(tmax, __shfl_xor(tmax, 32));
        float mn = fmaxf(m, tmax);
        float alpha = exp2f(m - mn);
        float e0 = exp2f(sv[0] - mn);
        float e1 = exp2f(sv[1] - mn);
        float e2 = exp2f(sv[2] - mn);
        float e3 = exp2f(sv[3] - mn);
        float rsum = e0 + e1 + e2 + e3;
        rsum += __shfl_xor(rsum, 16);
        rsum += __shfl_xor(rsum, 32);
        lsum = lsum * alpha + rsum;
        m = mn;
        o0 *= alpha; o1 *= alpha; o2 *= alpha; o3 *= alpha;

        short8 pfT;
        pfT[0] = f2bf(e0); pfT[1] = f2bf(e1); pfT[2] = f2bf(e2); pfT[3] = f2bf(e3);
        pfT[4] = 0; pfT[5] = 0; pfT[6] = 0; pfT[7] = 0;

        const float* vt = vnew + (size_t)(b * NS) * HID + h * HD;
        #define LOADVT(dst, dcol) do { \
            dst[0] = f2bf(vt[(size_t)((g << 2) + 0) * HID + (dcol)]); \
            dst[1] = f2bf(vt[(size_t)((g << 2) + 1) * HID + (dcol)]); \
            dst[2] = f2bf(vt[(size_t)((g << 2) + 2) * HID + (dcol)]); \
            dst[3] = f2bf(vt[(size_t)((g << 2) + 3) * HID + (dcol)]); \
            dst[4] = 0; dst[5] = 0; dst[6] = 0; dst[7] = 0; \
        } while (0)
        short8 vv0, vv1, vv2, vv3;
        LOADVT(vv0, lq); LOADVT(vv1, 16 + lq); LOADVT(vv2, 32 + lq); LOADVT(vv3, 48 + lq);
        #undef LOADVT
        o0 = MFMA(vv0, pfT, o0);
        o1 = MFMA(vv1, pfT, o1);
        o2 = MFMA(vv2, pfT, o2);
        o3 = MFMA(vv3, pfT, o3);
    }

    // ---- merge the 4 wave-partials via LDS; write block partial ----
    __shared__ float s_o[4][16][64];
    __shared__ float s_m[4][16];
    __shared__ float s_l[4][16];
    #define STO(ov, dt) do { \
        s_o[wave][lq][(dt) * 16 + (g << 2) + 0] = ov[0]; \
        s_o[wave][lq][(dt) * 16 + (g << 2) + 1] = ov[1]; \
        s_o[wave][lq][(dt) * 16 + (g << 2) + 2] = ov[2]; \
        s_o[wave][lq][(dt) * 16 + (g << 2) + 3] = ov[3]; \
    } while (0)
    STO(o0, 0); STO(o1, 1); STO(o2, 2); STO(o3, 3);
    #undef STO
    if (g == 0) { s_m[wave][lq] = m; s_l[wave][lq] = lsum; }
    __syncthreads();

    if (wave == 0) {
        float M = fmaxf(fmaxf(s_m[0][lq], s_m[1][lq]), fmaxf(s_m[2][lq], s_m[3][lq]));
        float aw0 = exp2f(s_m[0][lq] - M);
        float aw1 = exp2f(s_m[1][lq] - M);
        float aw2 = exp2f(s_m[2][lq] - M);
        float aw3 = exp2f(s_m[3][lq] - M);
        float L = aw0 * s_l[0][lq] + aw1 * s_l[1][lq] + aw2 * s_l[2][lq] + aw3 * s_l[3][lq];
        float* pbase = parts + (size_t)bid * PART_STRIDE;
        if (g == 0) { pbase[lq] = M; pbase[16 + lq] = L; }
        for (int dd = 0; dd < 16; ++dd) {
            int di = g * 16 + dd;
            float v = aw0 * s_o[0][lq][di] + aw1 * s_o[1][lq][di] +
                      aw2 * s_o[2][lq][di] + aw3 * s_o[3][lq][di];
            pbase[32 + lq * 64 + di] = v;
        }
    }
}

// ---------------- merge the 8 split-partials per (b,h) -------------------
__global__ __launch_bounds__(256) void merge_kernel(const float* __restrict__ parts,
                                                    short* __restrict__ attnb) {
    int bh = blockIdx.x;            // b*32 + h
    int tid = threadIdx.x;
    int qi = tid >> 4, ds = (tid & 15) * 4;
    const float* pb0 = parts + (size_t)(bh * NSPLIT) * PART_STRIDE;

    float M = -__builtin_inff();
    #pragma unroll
    for (int i = 0; i < NSPLIT; ++i)
        M = fmaxf(M, pb0[(size_t)i * PART_STRIDE + qi]);

    float aw0, aw1, aw2, aw3, aw4, aw5, aw6, aw7;
    float L = 0.f;
    #define AW(i, awv) do { \
        awv = exp2f(pb0[(size_t)(i) * PART_STRIDE + qi] - M); \
        L += awv * pb0[(size_t)(i) * PART_STRIDE + 16 + qi]; \
    } while (0)
    AW(0, aw0); AW(1, aw1); AW(2, aw2); AW(3, aw3);
    AW(4, aw4); AW(5, aw5); AW(6, aw6); AW(7, aw7);
    #undef AW
    float inv = 1.0f / L;

    int b = bh >> 5, h = bh & 31;
    int base = 32 + qi * 64 + ds;
    short4v o;
    #pragma unroll
    for (int r = 0; r < 4; ++r) {
        float v = aw0 * pb0[(size_t)0 * PART_STRIDE + base + r]
                + aw1 * pb0[(size_t)1 * PART_STRIDE + base + r]
                + aw2 * pb0[(size_t)2 * PART_STRIDE + base + r]
                + aw3 * pb0[(size_t)3 * PART_STRIDE + base + r]
                + aw4 * pb0[(size_t)4 * PART_STRIDE + base + r]
                + aw5 * pb0[(size_t)5 * PART_STRIDE + base + r]
                + aw6 * pb0[(size_t)6 * PART_STRIDE + base + r]
                + aw7 * pb0[(size_t)7 * PART_STRIDE + base + r];
        o[r] = f2bf(v * inv);
    }
    *reinterpret_cast<short4v*>(attnb + (size_t)(b * NS + qi) * HID + h * HD + ds) = o;
}

extern "C" void kernel_launch(void* const* d_in, const int* in_sizes, int n_in,
                              void* d_out, int out_size, void* d_ws, size_t ws_size,
                              hipStream_t stream) {
    const float* hs     = (const float*)d_in[0];
    const float* past_k = (const float*)d_in[1];
    const float* past_v = (const float*)d_in[2];
    const float* wq     = (const float*)d_in[3];
    const float* wk     = (const float*)d_in[4];
    const float* wv     = (const float*)d_in[5];
    const float* wo     = (const float*)d_in[6];
    float* out = (float*)d_out;

    float* qb = (float*)d_ws;                 // 128x2048 f32
    float* kn = qb + 128 * 2048;              // 128x2048 f32
    float* vn = kn + 128 * 2048;              // 128x2048 f32
    short* hsb   = (short*)(vn + 128 * 2048); // 128x2048 bf16
    short* attnb = hsb + 128 * 2048;          // 128x2048 bf16
    float* parts = (float*)(attnb + 128 * 2048); // 2048 * PART_STRIDE f32

    // zero atomic-accumulated outputs (graph-capture-safe async memsets)
    hipMemsetAsync(qb, 0, (size_t)3 * 128 * 2048 * sizeof(float), stream);
    hipMemsetAsync(out, 0, (size_t)128 * 2048 * sizeof(float), stream);

    cvt_kernel<<<256, 256, 0, stream>>>(hs, hsb);
    proj_kernel<<<1536, 128, 0, stream>>>(hsb, wq, wk, wv, qb, kn, vn);
    attn_kernel<<<256 * NSPLIT, 256, 0, stream>>>(qb, kn, vn, past_k, past_v, parts);
    merge_kernel<<<256, 256, 0, stream>>>(parts, attnb);
    proj_kernel<<<512, 128, 0, stream>>>(attnb, wo, wo, wo, out, out, out);
}

// Round 6
// 172.830 us; speedup vs baseline: 1.3231x; 1.3231x over previous
//
#include <hip/hip_runtime.h>
#include <hip/hip_bf16.h>
#include <stdint.h>

#define HID 2048
#define NH  32
#define HD  64
#define NB  8
#define NS  16
#define PAST 4096

// log2(e) / sqrt(D) = 1.4426950408889634 / 8
#define QSCALE 0.18033688011112042591f

typedef __attribute__((ext_vector_type(8))) short short8;
typedef __attribute__((ext_vector_type(4))) short short4v;
typedef __attribute__((ext_vector_type(4))) float f32x4;

#define MFMA(a, b, c) __builtin_amdgcn_mfma_f32_16x16x32_bf16((a), (b), (c), 0, 0, 0)

#define PART_STRIDE 1088  // 16 m + 16 l + 16*64 O + pad, floats
#define NSPLIT 8          // attn splits per (b,h); 512 pos per split

static __device__ __forceinline__ short f2bf(float f) {
    __hip_bfloat16 h = __float2bfloat16(f);
    return *reinterpret_cast<short*>(&h);
}

static __device__ __forceinline__ short8 pack8(float4 a, float4 b) {
    short8 r;
    r[0] = f2bf(a.x); r[1] = f2bf(a.y); r[2] = f2bf(a.z); r[3] = f2bf(a.w);
    r[4] = f2bf(b.x); r[5] = f2bf(b.y); r[6] = f2bf(b.z); r[7] = f2bf(b.w);
    return r;
}

static __device__ __forceinline__ short8 pack8s(float4 a, float4 b, float s) {
    short8 r;
    r[0] = f2bf(a.x * s); r[1] = f2bf(a.y * s); r[2] = f2bf(a.z * s); r[3] = f2bf(a.w * s);
    r[4] = f2bf(b.x * s); r[5] = f2bf(b.y * s); r[6] = f2bf(b.z * s); r[7] = f2bf(b.w * s);
    return r;
}

// ---------------- hidden fp32 -> bf16 ----------------
__global__ __launch_bounds__(256) void cvt_kernel(const float* __restrict__ in,
                                                  short* __restrict__ out) {
    int i = (blockIdx.x * 256 + threadIdx.x) * 4;
    float4 v = *reinterpret_cast<const float4*>(in + i);
    short4v o;
    o[0] = f2bf(v.x); o[1] = f2bf(v.y); o[2] = f2bf(v.z); o[3] = f2bf(v.w);
    *reinterpret_cast<short4v*>(out + i) = o;
}

// ------- Y += Xbf16 @ W^T  (M=128, K-split x4, N=16 per block), atomic -----
// blockIdx.x = mat*512 + strip*4 + ks.  128 threads (2 waves, M=64 each).
__global__ __launch_bounds__(128) void proj_kernel(
        const short* __restrict__ X,
        const float* __restrict__ W0, const float* __restrict__ W1,
        const float* __restrict__ W2,
        float* __restrict__ Y0, float* __restrict__ Y1, float* __restrict__ Y2) {
    int mat   = blockIdx.x >> 9;
    int rest  = blockIdx.x & 511;
    int strip = rest >> 2, ks = rest & 3;
    int nbase = strip * 16;
    int k0    = ks * 512;
    const float* W = (mat == 0) ? W0 : (mat == 1) ? W1 : W2;
    float*       Y = (mat == 0) ? Y0 : (mat == 1) ? Y1 : Y2;

    int lane = threadIdx.x & 63;
    int wave = threadIdx.x >> 6;
    int lr = lane & 15, g = lane >> 4;

    f32x4 acc0 = {0.f, 0.f, 0.f, 0.f};
    f32x4 acc1 = {0.f, 0.f, 0.f, 0.f};
    f32x4 acc2 = {0.f, 0.f, 0.f, 0.f};
    f32x4 acc3 = {0.f, 0.f, 0.f, 0.f};

    const short* xr = X + (size_t)(wave * 64 + lr) * HID + g * 8 + k0;
    const float* wr = W + (size_t)(nbase + lr) * HID + g * 8 + k0;

    #pragma unroll 4
    for (int kc = 0; kc < 512; kc += 32) {
        float4 w0 = *reinterpret_cast<const float4*>(wr + kc);
        float4 w1 = *reinterpret_cast<const float4*>(wr + kc + 4);
        short8 bb = pack8(w0, w1);
        short8 a0 = *reinterpret_cast<const short8*>(xr + kc);
        short8 a1 = *reinterpret_cast<const short8*>(xr + (size_t)16 * HID + kc);
        short8 a2 = *reinterpret_cast<const short8*>(xr + (size_t)32 * HID + kc);
        short8 a3 = *reinterpret_cast<const short8*>(xr + (size_t)48 * HID + kc);
        acc0 = MFMA(a0, bb, acc0);
        acc1 = MFMA(a1, bb, acc1);
        acc2 = MFMA(a2, bb, acc2);
        acc3 = MFMA(a3, bb, acc3);
    }
    #define STACC(accv, f) do { \
        atomicAdd(&Y[(size_t)(wave * 64 + (f) * 16 + (g << 2) + 0) * HID + nbase + lr], accv[0]); \
        atomicAdd(&Y[(size_t)(wave * 64 + (f) * 16 + (g << 2) + 1) * HID + nbase + lr], accv[1]); \
        atomicAdd(&Y[(size_t)(wave * 64 + (f) * 16 + (g << 2) + 2) * HID + nbase + lr], accv[2]); \
        atomicAdd(&Y[(size_t)(wave * 64 + (f) * 16 + (g << 2) + 3) * HID + nbase + lr], accv[3]); \
    } while (0)
    STACC(acc0, 0); STACC(acc1, 1); STACC(acc2, 2); STACC(acc3, 3);
    #undef STACC
}

// ---------------- fused attention, 8 blocks per (b,h) -------------------
// blockIdx.x = bh*8 + split. 256 threads = 4 waves; wave w owns pos
// [split*512 + w*128, +128) = 2 tiles of 64.
// NOTE: launch_bounds min-waves stays 4 — the (256,8) variant caps VGPR at 64
// and the allocator spills ~100MB to scratch (R5). At 52 VGPR the HW still
// schedules 8 waves/SIMD (occupancy steps at 64 VGPR); LDS 16.9KB*8=135KB<160.
__global__ __launch_bounds__(256, 4) void attn_kernel(
        const float* __restrict__ q,
        const float* __restrict__ knew, const float* __restrict__ vnew,
        const float* __restrict__ pastK, const float* __restrict__ pastV,
        float* __restrict__ parts) {
    int bid = blockIdx.x;
    int bh = bid >> 3, split = bid & 7;
    int b = bh >> 5, h = bh & 31;
    int wave = threadIdx.x >> 6, lane = threadIdx.x & 63;
    int lq = lane & 15, g = lane >> 4;

    // Q fragments (B operand of swapped QK^T), pre-scaled by log2(e)/8
    const float* qp = q + (size_t)(b * NS + lq) * HID + h * HD + g * 8;
    short8 qf0, qf1;
    {
        float4 a0 = *reinterpret_cast<const float4*>(qp);
        float4 a1 = *reinterpret_cast<const float4*>(qp + 4);
        float4 a2 = *reinterpret_cast<const float4*>(qp + 32);
        float4 a3 = *reinterpret_cast<const float4*>(qp + 36);
        qf0 = pack8s(a0, a1, QSCALE);
        qf1 = pack8s(a2, a3, QSCALE);
    }

    f32x4 o0 = {0.f, 0.f, 0.f, 0.f};
    f32x4 o1 = {0.f, 0.f, 0.f, 0.f};
    f32x4 o2 = {0.f, 0.f, 0.f, 0.f};
    f32x4 o3 = {0.f, 0.f, 0.f, 0.f};
    float m = -__builtin_inff(), lsum = 0.0f;

    const float* kbase = pastK + (size_t)bh * PAST * HD + (size_t)(split * 512 + wave * 128) * HD;
    const float* vbase = pastV + (size_t)bh * PAST * HD + (size_t)(split * 512 + wave * 128) * HD;

    // V gather: dst[j] = V[kfo + (j>=4?16:0) + g*4 + (j&3)][dcol], bf16
    #define LOADV8(dst, vtp, kfo, dcol) do { \
        dst[0] = f2bf((vtp)[(size_t)((kfo) + (g << 2) + 0) * HD + (dcol)]); \
        dst[1] = f2bf((vtp)[(size_t)((kfo) + (g << 2) + 1) * HD + (dcol)]); \
        dst[2] = f2bf((vtp)[(size_t)((kfo) + (g << 2) + 2) * HD + (dcol)]); \
        dst[3] = f2bf((vtp)[(size_t)((kfo) + (g << 2) + 3) * HD + (dcol)]); \
        dst[4] = f2bf((vtp)[(size_t)((kfo) + 16 + (g << 2) + 0) * HD + (dcol)]); \
        dst[5] = f2bf((vtp)[(size_t)((kfo) + 16 + (g << 2) + 1) * HD + (dcol)]); \
        dst[6] = f2bf((vtp)[(size_t)((kfo) + 16 + (g << 2) + 2) * HD + (dcol)]); \
        dst[7] = f2bf((vtp)[(size_t)((kfo) + 16 + (g << 2) + 3) * HD + (dcol)]); \
    } while (0)

    #define QKSUB(scv, s2i) do { \
        const float* kr = kbase + (size_t)(pb + (s2i) * 16 + lq) * HD + (g << 3); \
        float4 ka = *reinterpret_cast<const float4*>(kr); \
        float4 kb2 = *reinterpret_cast<const float4*>(kr + 4); \
        float4 kc2 = *reinterpret_cast<const float4*>(kr + 32); \
        float4 kd2 = *reinterpret_cast<const float4*>(kr + 36); \
        short8 af0 = pack8(ka, kb2); \
        short8 af1 = pack8(kc2, kd2); \
        f32x4 sv = {0.f, 0.f, 0.f, 0.f}; \
        sv = MFMA(af0, qf0, sv); \
        sv = MFMA(af1, qf1, sv); \
        scv = sv; \
    } while (0)

    #define PEXP(dst, idx, sv, r) do { \
        float e = exp2f(sv[r] - mn); rsum += e; dst[idx] = f2bf(e); \
    } while (0)

    #pragma unroll 1
    for (int t = 0; t < 2; ++t) {
        int pb = t * 64;

        // ---- V fragments first (independent; loads overlap QK compute) ----
        const float* vt = vbase + (size_t)pb * HD;
        short8 vf0, vf1, vf2, vf3, vf4, vf5, vf6, vf7;
        LOADV8(vf0, vt, 0,  lq);       LOADV8(vf1, vt, 32, lq);
        LOADV8(vf2, vt, 0,  16 + lq);  LOADV8(vf3, vt, 32, 16 + lq);
        LOADV8(vf4, vt, 0,  32 + lq);  LOADV8(vf5, vt, 32, 32 + lq);
        LOADV8(vf6, vt, 0,  48 + lq);  LOADV8(vf7, vt, 32, 48 + lq);

        // ---- scores: S^T[pos][q] via mfma(K_tile, Q) ----
        f32x4 sc0, sc1, sc2, sc3;
        QKSUB(sc0, 0); QKSUB(sc1, 1); QKSUB(sc2, 2); QKSUB(sc3, 3);

        // ---- online softmax (per query = lane&15, partners l^16, l^32) ----
        float tmax = fmaxf(
            fmaxf(fmaxf(fmaxf(sc0[0], sc0[1]), fmaxf(sc0[2], sc0[3])),
                  fmaxf(fmaxf(sc1[0], sc1[1]), fmaxf(sc1[2], sc1[3]))),
            fmaxf(fmaxf(fmaxf(sc2[0], sc2[1]), fmaxf(sc2[2], sc2[3])),
                  fmaxf(fmaxf(sc3[0], sc3[1]), fmaxf(sc3[2], sc3[3]))));
        tmax = fmaxf(tmax, __shfl_xor(tmax, 16));
        tmax = fmaxf(tmax, __shfl_xor(tmax, 32));
        float mn = fmaxf(m, tmax);
        float alpha = exp2f(m - mn);
        float rsum = 0.f;
        short8 pf0, pf1;
        PEXP(pf0, 0, sc0, 0); PEXP(pf0, 1, sc0, 1); PEXP(pf0, 2, sc0, 2); PEXP(pf0, 3, sc0, 3);
        PEXP(pf0, 4, sc1, 0); PEXP(pf0, 5, sc1, 1); PEXP(pf0, 6, sc1, 2); PEXP(pf0, 7, sc1, 3);
        PEXP(pf1, 0, sc2, 0); PEXP(pf1, 1, sc2, 1); PEXP(pf1, 2, sc2, 2); PEXP(pf1, 3, sc2, 3);
        PEXP(pf1, 4, sc3, 0); PEXP(pf1, 5, sc3, 1); PEXP(pf1, 6, sc3, 2); PEXP(pf1, 7, sc3, 3);
        rsum += __shfl_xor(rsum, 16);
        rsum += __shfl_xor(rsum, 32);
        lsum = lsum * alpha + rsum;
        m = mn;
        o0 *= alpha; o1 *= alpha; o2 *= alpha; o3 *= alpha;

        // ---- PV: O^T[d][q] += V^T frags x P^T ----
        o0 = MFMA(vf0, pf0, o0); o0 = MFMA(vf1, pf1, o0);
        o1 = MFMA(vf2, pf0, o1); o1 = MFMA(vf3, pf1, o1);
        o2 = MFMA(vf4, pf0, o2); o2 = MFMA(vf5, pf1, o2);
        o3 = MFMA(vf6, pf0, o3); o3 = MFMA(vf7, pf1, o3);
    }

    // ---- the 16 new tokens (wave 0 of split-0 block) ----
    if (split == 0 && wave == 0) {
        const float* kr = knew + (size_t)(b * NS + lq) * HID + h * HD + g * 8;
        float4 ka = *reinterpret_cast<const float4*>(kr);
        float4 kb2 = *reinterpret_cast<const float4*>(kr + 4);
        float4 kc2 = *reinterpret_cast<const float4*>(kr + 32);
        float4 kd2 = *reinterpret_cast<const float4*>(kr + 36);
        short8 af0 = pack8(ka, kb2);
        short8 af1 = pack8(kc2, kd2);
        f32x4 sv = {0.f, 0.f, 0.f, 0.f};
        sv = MFMA(af0, qf0, sv);
        sv = MFMA(af1, qf1, sv);

        float tmax = fmaxf(fmaxf(sv[0], sv[1]), fmaxf(sv[2], sv[3]));
        tmax = fmaxf(tmax, __shfl_xor(tmax, 16));
        tmax = fmaxf(tmax, __shfl_xor(tmax, 32));
        float mn = fmaxf(m, tmax);
        float alpha = exp2f(m - mn);
        float e0 = exp2f(sv[0] - mn);
        float e1 = exp2f(sv[1] - mn);
        float e2 = exp2f(sv[2] - mn);
        float e3 = exp2f(sv[3] - mn);
        float rsum = e0 + e1 + e2 + e3;
        rsum += __shfl_xor(rsum, 16);
        rsum += __shfl_xor(rsum, 32);
        lsum = lsum * alpha + rsum;
        m = mn;
        o0 *= alpha; o1 *= alpha; o2 *= alpha; o3 *= alpha;

        short8 pfT;
        pfT[0] = f2bf(e0); pfT[1] = f2bf(e1); pfT[2] = f2bf(e2); pfT[3] = f2bf(e3);
        pfT[4] = 0; pfT[5] = 0; pfT[6] = 0; pfT[7] = 0;

        const float* vt = vnew + (size_t)(b * NS) * HID + h * HD;
        #define LOADVT(dst, dcol) do { \
            dst[0] = f2bf(vt[(size_t)((g << 2) + 0) * HID + (dcol)]); \
            dst[1] = f2bf(vt[(size_t)((g << 2) + 1) * HID + (dcol)]); \
            dst[2] = f2bf(vt[(size_t)((g << 2) + 2) * HID + (dcol)]); \
            dst[3] = f2bf(vt[(size_t)((g << 2) + 3) * HID + (dcol)]); \
            dst[4] = 0; dst[5] = 0; dst[6] = 0; dst[7] = 0; \
        } while (0)
        short8 vv0, vv1, vv2, vv3;
        LOADVT(vv0, lq); LOADVT(vv1, 16 + lq); LOADVT(vv2, 32 + lq); LOADVT(vv3, 48 + lq);
        #undef LOADVT
        o0 = MFMA(vv0, pfT, o0);
        o1 = MFMA(vv1, pfT, o1);
        o2 = MFMA(vv2, pfT, o2);
        o3 = MFMA(vv3, pfT, o3);
    }

    // ---- merge the 4 wave-partials via LDS; write block partial ----
    __shared__ float s_o[4][16][64];
    __shared__ float s_m[4][16];
    __shared__ float s_l[4][16];
    #define STO(ov, dt) do { \
        s_o[wave][lq][(dt) * 16 + (g << 2) + 0] = ov[0]; \
        s_o[wave][lq][(dt) * 16 + (g << 2) + 1] = ov[1]; \
        s_o[wave][lq][(dt) * 16 + (g << 2) + 2] = ov[2]; \
        s_o[wave][lq][(dt) * 16 + (g << 2) + 3] = ov[3]; \
    } while (0)
    STO(o0, 0); STO(o1, 1); STO(o2, 2); STO(o3, 3);
    #undef STO
    if (g == 0) { s_m[wave][lq] = m; s_l[wave][lq] = lsum; }
    __syncthreads();

    if (wave == 0) {
        float M = fmaxf(fmaxf(s_m[0][lq], s_m[1][lq]), fmaxf(s_m[2][lq], s_m[3][lq]));
        float aw0 = exp2f(s_m[0][lq] - M);
        float aw1 = exp2f(s_m[1][lq] - M);
        float aw2 = exp2f(s_m[2][lq] - M);
        float aw3 = exp2f(s_m[3][lq] - M);
        float L = aw0 * s_l[0][lq] + aw1 * s_l[1][lq] + aw2 * s_l[2][lq] + aw3 * s_l[3][lq];
        float* pbase = parts + (size_t)bid * PART_STRIDE;
        if (g == 0) { pbase[lq] = M; pbase[16 + lq] = L; }
        for (int dd = 0; dd < 16; ++dd) {
            int di = g * 16 + dd;
            float v = aw0 * s_o[0][lq][di] + aw1 * s_o[1][lq][di] +
                      aw2 * s_o[2][lq][di] + aw3 * s_o[3][lq][di];
            pbase[32 + lq * 64 + di] = v;
        }
    }
}

// ---------------- merge the 8 split-partials per (b,h) -------------------
__global__ __launch_bounds__(256) void merge_kernel(const float* __restrict__ parts,
                                                    short* __restrict__ attnb) {
    int bh = blockIdx.x;            // b*32 + h
    int tid = threadIdx.x;
    int qi = tid >> 4, ds = (tid & 15) * 4;
    const float* pb0 = parts + (size_t)(bh * NSPLIT) * PART_STRIDE;

    float M = -__builtin_inff();
    #pragma unroll
    for (int i = 0; i < NSPLIT; ++i)
        M = fmaxf(M, pb0[(size_t)i * PART_STRIDE + qi]);

    float aw0, aw1, aw2, aw3, aw4, aw5, aw6, aw7;
    float L = 0.f;
    #define AW(i, awv) do { \
        awv = exp2f(pb0[(size_t)(i) * PART_STRIDE + qi] - M); \
        L += awv * pb0[(size_t)(i) * PART_STRIDE + 16 + qi]; \
    } while (0)
    AW(0, aw0); AW(1, aw1); AW(2, aw2); AW(3, aw3);
    AW(4, aw4); AW(5, aw5); AW(6, aw6); AW(7, aw7);
    #undef AW
    float inv = 1.0f / L;

    int b = bh >> 5, h = bh & 31;
    int base = 32 + qi * 64 + ds;
    short4v o;
    #pragma unroll
    for (int r = 0; r < 4; ++r) {
        float v = aw0 * pb0[(size_t)0 * PART_STRIDE + base + r]
                + aw1 * pb0[(size_t)1 * PART_STRIDE + base + r]
                + aw2 * pb0[(size_t)2 * PART_STRIDE + base + r]
                + aw3 * pb0[(size_t)3 * PART_STRIDE + base + r]
                + aw4 * pb0[(size_t)4 * PART_STRIDE + base + r]
                + aw5 * pb0[(size_t)5 * PART_STRIDE + base + r]
                + aw6 * pb0[(size_t)6 * PART_STRIDE + base + r]
                + aw7 * pb0[(size_t)7 * PART_STRIDE + base + r];
        o[r] = f2bf(v * inv);
    }
    *reinterpret_cast<short4v*>(attnb + (size_t)(b * NS + qi) * HID + h * HD + ds) = o;
}

extern "C" void kernel_launch(void* const* d_in, const int* in_sizes, int n_in,
                              void* d_out, int out_size, void* d_ws, size_t ws_size,
                              hipStream_t stream) {
    const float* hs     = (const float*)d_in[0];
    const float* past_k = (const float*)d_in[1];
    const float* past_v = (const float*)d_in[2];
    const float* wq     = (const float*)d_in[3];
    const float* wk     = (const float*)d_in[4];
    const float* wv     = (const float*)d_in[5];
    const float* wo     = (const float*)d_in[6];
    float* out = (float*)d_out;

    float* qb = (float*)d_ws;                 // 128x2048 f32
    float* kn = qb + 128 * 2048;              // 128x2048 f32
    float* vn = kn + 128 * 2048;              // 128x2048 f32
    short* hsb   = (short*)(vn + 128 * 2048); // 128x2048 bf16
    short* attnb = hsb + 128 * 2048;          // 128x2048 bf16
    float* parts = (float*)(attnb + 128 * 2048); // 2048 * PART_STRIDE f32

    // zero atomic-accumulated outputs (graph-capture-safe async memsets)
    hipMemsetAsync(qb, 0, (size_t)3 * 128 * 2048 * sizeof(float), stream);
    hipMemsetAsync(out, 0, (size_t)128 * 2048 * sizeof(float), stream);

    cvt_kernel<<<256, 256, 0, stream>>>(hs, hsb);
    proj_kernel<<<1536, 128, 0, stream>>>(hsb, wq, wk, wv, qb, kn, vn);
    attn_kernel<<<256 * NSPLIT, 256, 0, stream>>>(qb, kn, vn, past_k, past_v, parts);
    merge_kernel<<<256, 256, 0, stream>>>(parts, attnb);
    proj_kernel<<<512, 128, 0, stream>>>(attnb, wo, wo, wo, out, out, out);
}